// Round 1
// baseline (1005.030 us; speedup 1.0000x reference)
//
#include <hip/hip_runtime.h>

// Problem constants (from reference): B,S,NODE,DEP,R,L,E = 32,1024,256,64,50,16,128
constexpr int B_ = 32;
constexpr int S_ = 1024;
constexpr int NODE_ = 256;
constexpr int DEP_ = 64;
constexpr int R_ = 50;
constexpr int L_ = 16;
constexpr int E_ = 128;
constexpr int FEAT_ = NODE_ + DEP_;   // 320
constexpr int NEDGE_ = B_ * E_;       // 4096 edges per layer

// ---------------------------------------------------------------------------
// K0: zero the child state [B*S, DEP] (ws is poisoned 0xAA before every call)
// ---------------------------------------------------------------------------
__global__ void k_zero(float* __restrict__ p, int n) {
  int i = blockIdx.x * blockDim.x + threadIdx.x;
  if (i < n) p[i] = 0.0f;
}

// ---------------------------------------------------------------------------
// K1: clear accum/cnt only for head nodes touched by this layer.
// Racy identical-value writes (multiple edges, same head) are benign.
// One thread per (edge, k): 4096*64 = 262144 threads.
// ---------------------------------------------------------------------------
__global__ void k_clear(const int* __restrict__ heads, int l,
                        float* __restrict__ accum, float* __restrict__ cnt) {
  int tid = blockIdx.x * blockDim.x + threadIdx.x;
  int edge = tid >> 6;
  int k = tid & 63;
  int b = edge >> 7;          // E_ = 128
  int e = edge & (E_ - 1);
  int h = heads[(b * L_ + l) * E_ + e];
  int idx = b * S_ + h;
  accum[idx * DEP_ + k] = 0.0f;
  if (k == 0) cnt[idx] = 0.0f;
}

// ---------------------------------------------------------------------------
// K2: per-edge relation matvec msg = W[r] @ [ctx[t]; child[t]], then
// atomic scatter-add onto accum[head] and bump cnt[head].
// One wave (64 lanes) per edge; lane k computes msg[k] (a 320-wide dot).
// W row loads: per-lane sequential float4 (rows 1280B apart, L2-resident,
// dep_W total is 4.1 MB). feat loads are wave-broadcast (all lanes same addr).
// ---------------------------------------------------------------------------
__global__ void k_msg(const float* __restrict__ context,
                      const float* __restrict__ dep_W,
                      const int* __restrict__ heads,
                      const int* __restrict__ tails,
                      const int* __restrict__ rels,
                      const float* __restrict__ child,
                      int l,
                      float* __restrict__ accum, float* __restrict__ cnt) {
  int tid = blockIdx.x * blockDim.x + threadIdx.x;
  int edge = tid >> 6;
  int lane = tid & 63;
  int b = edge >> 7;
  int e = edge & (E_ - 1);
  int base = (b * L_ + l) * E_ + e;
  int h = heads[base];
  int t = tails[base];
  int r = rels[base];

  const float* Wrow = dep_W + (size_t)(r * DEP_ + lane) * FEAT_;
  const float* ctx  = context + (size_t)(b * S_ + t) * NODE_;
  const float* chd  = child   + (size_t)(b * S_ + t) * DEP_;

  float acc = 0.0f;
#pragma unroll 4
  for (int d = 0; d < NODE_; d += 4) {
    float4 w = *(const float4*)(Wrow + d);
    float4 f = *(const float4*)(ctx + d);
    acc += w.x * f.x + w.y * f.y + w.z * f.z + w.w * f.w;
  }
#pragma unroll
  for (int j = 0; j < DEP_; j += 4) {
    float4 w = *(const float4*)(Wrow + NODE_ + j);
    float4 f = *(const float4*)(chd + j);
    acc += w.x * f.x + w.y * f.y + w.z * f.z + w.w * f.w;
  }

  int idx = b * S_ + h;
  atomicAdd(&accum[idx * DEP_ + lane], acc);
  if (lane == 0) atomicAdd(&cnt[idx], 1.0f);
}

// ---------------------------------------------------------------------------
// K3: assignment semantics — heads touched this layer get the average.
// Multiple edges with the same head write the identical quotient (benign).
// ---------------------------------------------------------------------------
__global__ void k_assign(const int* __restrict__ heads, int l,
                         const float* __restrict__ accum,
                         const float* __restrict__ cnt,
                         float* __restrict__ child) {
  int tid = blockIdx.x * blockDim.x + threadIdx.x;
  int edge = tid >> 6;
  int k = tid & 63;
  int b = edge >> 7;
  int e = edge & (E_ - 1);
  int h = heads[(b * L_ + l) * E_ + e];
  int idx = b * S_ + h;
  float c = cnt[idx];
  child[idx * DEP_ + k] = accum[idx * DEP_ + k] / fmaxf(c, 1.0f);
}

// ---------------------------------------------------------------------------
// K4: out[b,s,:] = concat(context[b,s,:], child[b,s,:])
// One block (320 threads = 5 waves) per (b,s) row; coalesced.
// ---------------------------------------------------------------------------
__global__ void k_out(const float* __restrict__ context,
                      const float* __restrict__ child,
                      float* __restrict__ out) {
  int row = blockIdx.x;      // 0 .. B*S-1
  int c = threadIdx.x;       // 0 .. 319
  float v = (c < NODE_) ? context[(size_t)row * NODE_ + c]
                        : child[(size_t)row * DEP_ + (c - NODE_)];
  out[(size_t)row * FEAT_ + c] = v;
}

extern "C" void kernel_launch(void* const* d_in, const int* in_sizes, int n_in,
                              void* d_out, int out_size, void* d_ws, size_t ws_size,
                              hipStream_t stream) {
  const float* context = (const float*)d_in[0];  // [B,S,NODE] fp32
  const float* dep_W   = (const float*)d_in[1];  // [R,DEP,NODE+DEP] fp32
  const int*   heads   = (const int*)d_in[2];    // [B,L,E] i32
  const int*   tails   = (const int*)d_in[3];
  const int*   rels    = (const int*)d_in[4];
  float* out = (float*)d_out;                    // [B,S,NODE+DEP] fp32

  // Workspace layout (fp32): child [B*S*DEP] | accum [B*S*DEP] | cnt [B*S]
  float* child = (float*)d_ws;
  float* accum = child + (size_t)B_ * S_ * DEP_;
  float* cnt   = accum + (size_t)B_ * S_ * DEP_;

  // K0: zero child (2M elements)
  {
    int n = B_ * S_ * DEP_;
    k_zero<<<(n + 255) / 256, 256, 0, stream>>>(child, n);
  }

  // 16 sequential layers; stream order provides the inter-kernel dependency.
  int threads_per_layer = NEDGE_ * 64;   // 262144
  int blocks = threads_per_layer / 256;  // 1024
  for (int l = 0; l < L_; ++l) {
    k_clear<<<blocks, 256, 0, stream>>>(heads, l, accum, cnt);
    k_msg<<<blocks, 256, 0, stream>>>(context, dep_W, heads, tails, rels,
                                      child, l, accum, cnt);
    k_assign<<<blocks, 256, 0, stream>>>(heads, l, accum, cnt, child);
  }

  // K5: assemble output
  k_out<<<B_ * S_, FEAT_, 0, stream>>>(context, child, out);
}

// Round 2
// 681.027 us; speedup vs baseline: 1.4758x; 1.4758x over previous
//
#include <hip/hip_runtime.h>

// Problem constants: B,S,NODE,DEP,R,L,E = 32,1024,256,64,50,16,128
constexpr int B_ = 32;
constexpr int S_ = 1024;
constexpr int NODE_ = 256;
constexpr int DEP_ = 64;
constexpr int R_ = 50;
constexpr int L_ = 16;
constexpr int E_ = 128;
constexpr int FEAT_ = NODE_ + DEP_;     // 320
constexpr int NEDGE_ = B_ * E_;         // 4096 edges per layer
constexpr int CH_ = 8;                  // edges per relation-chunk
constexpr int NCH_ = 576;               // max chunks/layer (sum ceil(n_r/8) <= 555)
constexpr int NSLICE_ = 5;              // 320 / 64 d-slices

// ---------------------------------------------------------------------------
// Workspace layout (floats). child|accum0|cnt0 contiguous so one zero pass
// covers them.  WT = dep_W transposed to [r][d][k] for coalesced lane-k loads.
// ---------------------------------------------------------------------------
constexpr size_t OFF_CHILD  = 0;
constexpr size_t N_CHILD    = (size_t)B_ * S_ * DEP_;          // 2,097,152
constexpr size_t OFF_ACC0   = OFF_CHILD + N_CHILD;
constexpr size_t N_ACC      = (size_t)B_ * S_ * DEP_;
constexpr size_t OFF_CNT0   = OFF_ACC0 + N_ACC;
constexpr size_t N_CNT      = (size_t)B_ * S_;                 // 32,768
constexpr size_t OFF_ACC1   = OFF_CNT0 + N_CNT;
constexpr size_t OFF_CNT1   = OFF_ACC1 + N_ACC;
constexpr size_t OFF_WT     = OFF_CNT1 + N_CNT;
constexpr size_t N_WT       = (size_t)R_ * FEAT_ * DEP_;       // 1,024,000
constexpr size_t OFF_SORT   = OFF_WT + N_WT;                   // ints
constexpr size_t N_SORT     = (size_t)L_ * NEDGE_;             // 65,536
constexpr size_t OFF_CHUNK  = OFF_SORT + N_SORT;               // int4 entries
constexpr size_t N_CHUNK_I  = (size_t)L_ * NCH_ * 4;           // ints
constexpr size_t TOT_FUSED  = OFF_CHUNK + N_CHUNK_I;           // floats/ints
constexpr size_t TOT_UNFUSED_HI = OFF_ACC1;                    // if we skip acc1/cnt1
// (unfused still needs WT/sort/chunks; we relocate them low in that case)

// ---------------------------------------------------------------------------
// K0: zero a float region
// ---------------------------------------------------------------------------
__global__ void k_zero(float* __restrict__ p, int n) {
  int i = blockIdx.x * blockDim.x + threadIdx.x;
  if (i < n) p[i] = 0.0f;
}

// ---------------------------------------------------------------------------
// K_T: transpose dep_W [R][DEP][FEAT] -> WT [R][FEAT][DEP]  (coalesced writes)
// ---------------------------------------------------------------------------
__global__ void k_transpose(const float* __restrict__ W, float* __restrict__ WT) {
  int gid = blockIdx.x * blockDim.x + threadIdx.x;
  int total = R_ * FEAT_ * DEP_;
  if (gid >= total) return;
  int r = gid / (FEAT_ * DEP_);
  int rem = gid - r * (FEAT_ * DEP_);
  int d = rem >> 6;          // FEAT index
  int k = rem & 63;          // DEP index
  WT[gid] = W[(size_t)r * DEP_ * FEAT_ + (size_t)k * FEAT_ + d];
}

// ---------------------------------------------------------------------------
// K_B: per-layer relation binning + chunk table. One block per layer.
// chunk entry int4 {r, start, cnt, 0}; all NCH_ entries written every call
// (ws is re-poisoned before every timed launch).
// ---------------------------------------------------------------------------
__global__ void k_bin(const int* __restrict__ rels, int* __restrict__ sorted_eid,
                      int4* __restrict__ chunks) {
  int l = blockIdx.x;
  int tid = threadIdx.x;
  __shared__ int hist[R_], startA[R_], rank[R_];
  if (tid < R_) { hist[tid] = 0; rank[tid] = 0; }
  __syncthreads();
  for (int ed = tid; ed < NEDGE_; ed += blockDim.x) {
    int b = ed >> 7, e = ed & (E_ - 1);
    int r = rels[(b * L_ + l) * E_ + e];
    atomicAdd(&hist[r], 1);
  }
  __syncthreads();
  if (tid == 0) {
    int s = 0;
    for (int r = 0; r < R_; ++r) { startA[r] = s; s += hist[r]; }
  }
  __syncthreads();
  for (int ed = tid; ed < NEDGE_; ed += blockDim.x) {
    int b = ed >> 7, e = ed & (E_ - 1);
    int r = rels[(b * L_ + l) * E_ + e];
    int pos = startA[r] + atomicAdd(&rank[r], 1);
    sorted_eid[l * NEDGE_ + pos] = ed;
  }
  if (tid == 0) {
    int nc = 0;
    for (int r = 0; r < R_; ++r) {
      for (int c0 = 0; c0 < hist[r]; c0 += CH_) {
        int c = hist[r] - c0; if (c > CH_) c = CH_;
        chunks[l * NCH_ + nc] = make_int4(r, startA[r] + c0, c, 0);
        ++nc;
      }
    }
    for (; nc < NCH_; ++nc) chunks[l * NCH_ + nc] = make_int4(0, 0, 0, 0);
  }
}

// ---------------------------------------------------------------------------
// K_M: message GEMM. Block = 320 threads = 5 waves; one relation-chunk of <=8
// edges per block. Wave s register-caches WT slice [64 d][lane k] (coalesced),
// streams per-edge feats as wave-uniform scalar loads, LDS-combines the 5
// d-slice partials, then atomically scatters onto accum[head] (+cnt).
// ---------------------------------------------------------------------------
__global__ void __launch_bounds__(320) k_msg(
    const float* __restrict__ context, const float* __restrict__ WT,
    const int* __restrict__ heads, const int* __restrict__ tails,
    const float* __restrict__ child, const int* __restrict__ sorted_eid,
    const int4* __restrict__ chunks, int l,
    float* __restrict__ accum, float* __restrict__ cntbuf) {
  int4 ck = chunks[l * NCH_ + blockIdx.x];
  int r = ck.x, start = ck.y, ccnt = ck.z;
  if (ccnt == 0) return;

  int tid = threadIdx.x;
  int s = tid >> 6;          // wave / d-slice 0..4
  int k = tid & 63;          // lane / output row

  __shared__ int eids[CH_], ts[CH_];
  __shared__ float part[NSLICE_][CH_][DEP_];   // 10 KB
  if (tid < ccnt) {
    int ed = sorted_eid[l * NEDGE_ + start + tid];
    eids[tid] = ed;
    int b = ed >> 7, e = ed & (E_ - 1);
    ts[tid] = tails[(b * L_ + l) * E_ + e];
  }
  __syncthreads();

  // register-cache W slice: w[i] = WT[r][s*64+i][k]  (consecutive k coalesced)
  const float* WTs = WT + ((size_t)r * FEAT_ + s * 64) * DEP_ + k;
  float w[64];
#pragma unroll
  for (int i = 0; i < 64; ++i) w[i] = WTs[(size_t)i * DEP_];

  for (int j = 0; j < ccnt; ++j) {
    int ed = __builtin_amdgcn_readfirstlane(eids[j]);
    int t  = __builtin_amdgcn_readfirstlane(ts[j]);
    int b = ed >> 7;
    const float* f = (s < 4)
        ? context + ((size_t)(b * S_ + t) * NODE_ + s * 64)
        : child + (size_t)(b * S_ + t) * DEP_;
    float a0 = 0.f, a1 = 0.f, a2 = 0.f, a3 = 0.f;
#pragma unroll
    for (int i = 0; i < 64; i += 4) {
      a0 = fmaf(w[i + 0], f[i + 0], a0);
      a1 = fmaf(w[i + 1], f[i + 1], a1);
      a2 = fmaf(w[i + 2], f[i + 2], a2);
      a3 = fmaf(w[i + 3], f[i + 3], a3);
    }
    part[s][j][k] = (a0 + a1) + (a2 + a3);
  }
  __syncthreads();

  // combine 5 slices and scatter
  for (int idx = tid; idx < ccnt * DEP_; idx += 320) {
    int j = idx >> 6, k2 = idx & 63;
    float m = part[0][j][k2] + part[1][j][k2] + part[2][j][k2] +
              part[3][j][k2] + part[4][j][k2];
    int ed = eids[j];
    int b = ed >> 7, e = ed & (E_ - 1);
    int h = heads[(b * L_ + l) * E_ + e];
    size_t row = (size_t)b * S_ + h;
    atomicAdd(&accum[row * DEP_ + k2], m);
    if (k2 == 0) atomicAdd(&cntbuf[row], 1.0f);
  }
}

// ---------------------------------------------------------------------------
// K_A: assignment (avg) for touched heads; optionally clears the other-parity
// accum/cnt rows for layer l+1 (fused path; race-free via double buffering).
// Thread per (edge, k); duplicate heads write identical values (benign).
// ---------------------------------------------------------------------------
__global__ void k_avg(const int* __restrict__ heads, int l,
                      const float* __restrict__ accumP, const float* __restrict__ cntP,
                      float* __restrict__ child,
                      float* __restrict__ accumQ, float* __restrict__ cntQ,
                      int do_clear_next) {
  int gid = blockIdx.x * blockDim.x + threadIdx.x;
  int ed = gid >> 6, k = gid & 63;
  int b = ed >> 7, e = ed & (E_ - 1);
  int h = heads[(b * L_ + l) * E_ + e];
  size_t row = (size_t)b * S_ + h;
  float c = cntP[row];
  child[row * DEP_ + k] = accumP[row * DEP_ + k] / fmaxf(c, 1.0f);
  if (do_clear_next) {
    int h2 = heads[(b * L_ + (l + 1)) * E_ + e];
    size_t row2 = (size_t)b * S_ + h2;
    accumQ[row2 * DEP_ + k] = 0.0f;
    if (k == 0) cntQ[row2] = 0.0f;
  }
}

// ---------------------------------------------------------------------------
// K_C (unfused fallback): clear accum/cnt rows for this layer's heads
// ---------------------------------------------------------------------------
__global__ void k_clear(const int* __restrict__ heads, int l,
                        float* __restrict__ accum, float* __restrict__ cnt) {
  int tid = blockIdx.x * blockDim.x + threadIdx.x;
  int ed = tid >> 6, k = tid & 63;
  int b = ed >> 7, e = ed & (E_ - 1);
  int h = heads[(b * L_ + l) * E_ + e];
  size_t row = (size_t)b * S_ + h;
  accum[row * DEP_ + k] = 0.0f;
  if (k == 0) cnt[row] = 0.0f;
}

// ---------------------------------------------------------------------------
// K_O: out[b,s,:] = concat(context, child)
// ---------------------------------------------------------------------------
__global__ void k_out(const float* __restrict__ context,
                      const float* __restrict__ child,
                      float* __restrict__ out) {
  int row = blockIdx.x;
  int c = threadIdx.x;
  float v = (c < NODE_) ? context[(size_t)row * NODE_ + c]
                        : child[(size_t)row * DEP_ + (c - NODE_)];
  out[(size_t)row * FEAT_ + c] = v;
}

extern "C" void kernel_launch(void* const* d_in, const int* in_sizes, int n_in,
                              void* d_out, int out_size, void* d_ws, size_t ws_size,
                              hipStream_t stream) {
  const float* context = (const float*)d_in[0];
  const float* dep_W   = (const float*)d_in[1];
  const int*   heads   = (const int*)d_in[2];
  const int*   tails   = (const int*)d_in[3];
  const int*   rels    = (const int*)d_in[4];
  float* out = (float*)d_out;

  float* ws = (float*)d_ws;
  float* child  = ws + OFF_CHILD;
  float* accum0 = ws + OFF_ACC0;
  float* cnt0   = ws + OFF_CNT0;
  bool fused = ws_size >= TOT_FUSED * sizeof(float);
  float* accum1 = fused ? ws + OFF_ACC1 : accum0;
  float* cnt1   = fused ? ws + OFF_CNT1 : cnt0;
  // In unfused mode, relocate WT/sort/chunks where acc1 would live.
  size_t off_wt    = fused ? OFF_WT    : OFF_ACC1;
  float* WT        = ws + off_wt;
  int*   sorted    = (int*)(ws + off_wt + N_WT);
  int4*  chunks    = (int4*)(ws + off_wt + N_WT + N_SORT);

  // Prepasses (data-independent of child): transpose W, bin all 16 layers.
  {
    int totW = R_ * FEAT_ * DEP_;
    k_transpose<<<(totW + 255) / 256, 256, 0, stream>>>(dep_W, WT);
    k_bin<<<L_, 256, 0, stream>>>(rels, sorted, chunks);
    // zero child + accum0 + cnt0 (contiguous region)
    int n = (int)(N_CHILD + N_ACC + N_CNT);
    k_zero<<<(n + 255) / 256, 256, 0, stream>>>(child, n);
  }

  int blocks_edge = NEDGE_ * 64 / 256;   // 1024
  for (int l = 0; l < L_; ++l) {
    float* accP = (l & 1) ? accum1 : accum0;
    float* cntP = (l & 1) ? cnt1 : cnt0;
    float* accQ = (l & 1) ? accum0 : accum1;
    float* cntQ = (l & 1) ? cnt0 : cnt1;
    if (!fused && l > 0) {
      k_clear<<<blocks_edge, 256, 0, stream>>>(heads, l, accP, cntP);
    }
    k_msg<<<NCH_, 320, 0, stream>>>(context, WT, heads, tails, child,
                                    sorted, chunks, l, accP, cntP);
    int do_clear = (fused && (l + 1 < L_)) ? 1 : 0;
    k_avg<<<blocks_edge, 256, 0, stream>>>(heads, l, accP, cntP, child,
                                           accQ, cntQ, do_clear);
  }

  k_out<<<B_ * S_, FEAT_, 0, stream>>>(context, child, out);
}

// Round 3
// 540.663 us; speedup vs baseline: 1.8589x; 1.2596x over previous
//
#include <hip/hip_runtime.h>

// Problem constants: B,S,NODE,DEP,R,L,E = 32,1024,256,64,50,16,128
constexpr int B_ = 32;
constexpr int S_ = 1024;
constexpr int NODE_ = 256;
constexpr int DEP_ = 64;
constexpr int R_ = 50;
constexpr int L_ = 16;
constexpr int E_ = 128;
constexpr int FEAT_ = NODE_ + DEP_;     // 320
constexpr int NEDGE_ = B_ * E_;         // 4096 edges per layer
constexpr int CH_ = 16;                 // edges per relation-chunk
constexpr int NCH_ = 320;               // max chunks/layer (sum ceil(n_r/16) <= 303)
constexpr int NSLICE_ = 5;              // 320/64 d-slices (one per wave)

// ---------------------------------------------------------------------------
// Workspace layout (floats). child|accum0|cnt0 contiguous (one zero pass).
// WT2 = dep_W re-laid-out to [r][i4][k][4] (i4 = d/4) so a wave's W-cache
// load is 16 coalesced dwordx4 (lane k reads 16B at stride-16B across lanes).
// ---------------------------------------------------------------------------
constexpr size_t N_CHILD   = (size_t)B_ * S_ * DEP_;          // 2,097,152
constexpr size_t N_ACC     = N_CHILD;
constexpr size_t N_CNT     = (size_t)B_ * S_;                 // 32,768
constexpr size_t OFF_CHILD = 0;
constexpr size_t OFF_ACC0  = OFF_CHILD + N_CHILD;
constexpr size_t OFF_CNT0  = OFF_ACC0 + N_ACC;
constexpr size_t OFF_ACC1  = OFF_CNT0 + N_CNT;
constexpr size_t OFF_CNT1  = OFF_ACC1 + N_ACC;
constexpr size_t OFF_WT    = OFF_CNT1 + N_CNT;
constexpr size_t N_WT      = (size_t)R_ * FEAT_ * DEP_;       // 1,024,000
constexpr size_t OFF_SORT  = OFF_WT + N_WT;                   // ints
constexpr size_t N_SORT    = (size_t)L_ * NEDGE_;             // 65,536
constexpr size_t OFF_CHUNK = OFF_SORT + N_SORT;               // int4 entries
constexpr size_t N_CHUNK_I = (size_t)L_ * NCH_ * 4;

__global__ void k_zero(float* __restrict__ p, int n) {
  int i = blockIdx.x * blockDim.x + threadIdx.x;
  if (i < n) p[i] = 0.0f;
}

// ---------------------------------------------------------------------------
// K_T: dep_W [R][DEP=k][FEAT=d] -> WT2 [r][i4=d/4][k][c=d%4]; coalesced writes
// ---------------------------------------------------------------------------
__global__ void k_transpose(const float* __restrict__ W, float* __restrict__ WT2) {
  int gid = blockIdx.x * blockDim.x + threadIdx.x;
  int total = R_ * FEAT_ * DEP_;
  if (gid >= total) return;
  int r = gid / 20480;              // 80*64*4
  int rem = gid - r * 20480;
  int i4 = rem >> 8;                // 0..79
  int k = (rem >> 2) & 63;
  int c = rem & 3;
  WT2[gid] = W[((size_t)r * DEP_ + k) * FEAT_ + 4 * i4 + c];
}

// ---------------------------------------------------------------------------
// K_B: per-layer relation binning + chunk table. One block per layer, parallel
// hist/scatter via LDS atomics; short serial prefixes; parallel chunk emit.
// ---------------------------------------------------------------------------
__global__ void k_bin(const int* __restrict__ rels, int* __restrict__ sorted_eid,
                      int4* __restrict__ chunks) {
  int l = blockIdx.x, tid = threadIdx.x;   // 256 threads
  __shared__ int hist[R_], startA[R_], rank[R_], cstart[R_];
  __shared__ int ntot;
  if (tid < R_) { hist[tid] = 0; rank[tid] = 0; }
  __syncthreads();
  for (int ed = tid; ed < NEDGE_; ed += 256) {
    int b = ed >> 7, e = ed & (E_ - 1);
    atomicAdd(&hist[rels[(b * L_ + l) * E_ + e]], 1);
  }
  __syncthreads();
  if (tid == 0) {
    int s = 0, cs = 0;
    for (int r = 0; r < R_; ++r) {
      startA[r] = s; s += hist[r];
      cstart[r] = cs; cs += (hist[r] + CH_ - 1) / CH_;
    }
    ntot = cs;
  }
  __syncthreads();
  for (int ed = tid; ed < NEDGE_; ed += 256) {
    int b = ed >> 7, e = ed & (E_ - 1);
    int r = rels[(b * L_ + l) * E_ + e];
    int pos = startA[r] + atomicAdd(&rank[r], 1);
    sorted_eid[l * NEDGE_ + pos] = ed;
  }
  if (tid < R_) {
    int n = hist[tid], st = startA[tid], cs = cstart[tid];
    for (int m = 0; m * CH_ < n; ++m) {
      int c = n - m * CH_; if (c > CH_) c = CH_;
      chunks[l * NCH_ + cs + m] = make_int4(tid, st + m * CH_, c, 0);
    }
  }
  __syncthreads();
  for (int i = ntot + tid; i < NCH_; i += 256)
    chunks[l * NCH_ + i] = make_int4(0, 0, 0, 0);
}

// ---------------------------------------------------------------------------
// K_M: message matvecs for one relation-chunk (<=16 edges). 5 waves; wave s
// owns d-slice [64s,64s+64). W slice register-cached via 16 coalesced dwordx4.
// Feats staged in LDS (coalesced gathers), read back as b128 broadcasts.
// Partials combined through LDS, then scattered with global atomics.
// ---------------------------------------------------------------------------
__global__ void __launch_bounds__(320) k_msg(
    const float* __restrict__ context, const float* __restrict__ WT2,
    const int* __restrict__ heads, const int* __restrict__ tails,
    const float* __restrict__ child, const int* __restrict__ sorted_eid,
    const int4* __restrict__ chunks, int l,
    float* __restrict__ accum, float* __restrict__ cntbuf) {
  int4 ck = chunks[l * NCH_ + blockIdx.x];
  int r = ck.x, start = ck.y, ccnt = ck.z;
  if (ccnt == 0) return;

  int tid = threadIdx.x;
  int s = tid >> 6;        // wave / d-slice
  int k = tid & 63;        // lane / output row

  __shared__ int eids[CH_], ts[CH_];
  __shared__ float feat[CH_][FEAT_];            // 20 KB
  __shared__ float part[NSLICE_][CH_][DEP_];    // 20 KB
  if (tid < ccnt) {
    int ed = sorted_eid[l * NEDGE_ + start + tid];
    eids[tid] = ed;
    int b = ed >> 7, e = ed & (E_ - 1);
    ts[tid] = tails[(b * L_ + l) * E_ + e];
  }
  __syncthreads();

  // W register cache: w[i].{x,y,z,w} = W[r][k][64s + 4i + {0..3}]
  const float4* Wp = (const float4*)WT2 + ((size_t)r * 80 + s * 16) * 64 + k;
  float4 w[16];
#pragma unroll
  for (int i = 0; i < 16; ++i) w[i] = Wp[(size_t)i * 64];

  // Stage feats: feat[j][0:256)=ctx row, [256:320)=child row (coalesced)
#pragma unroll 4
  for (int j = 0; j < ccnt; ++j) {
    int b = eids[j] >> 7;
    int t = ts[j];
    feat[j][tid] = (tid < NODE_)
        ? context[((size_t)(b * S_ + t)) * NODE_ + tid]
        : child[((size_t)(b * S_ + t)) * DEP_ + (tid - NODE_)];
  }
  __syncthreads();

  for (int j = 0; j < ccnt; ++j) {
    const float4* f4 = (const float4*)&feat[j][s * 64];  // broadcast reads
    float a0 = 0.f, a1 = 0.f, a2 = 0.f, a3 = 0.f;
#pragma unroll
    for (int i = 0; i < 16; ++i) {
      float4 f = f4[i];
      a0 = fmaf(w[i].x, f.x, a0);
      a1 = fmaf(w[i].y, f.y, a1);
      a2 = fmaf(w[i].z, f.z, a2);
      a3 = fmaf(w[i].w, f.w, a3);
    }
    part[s][j][k] = (a0 + a1) + (a2 + a3);
  }
  __syncthreads();

  for (int idx = tid; idx < ccnt * DEP_; idx += 320) {
    int j = idx >> 6, k2 = idx & 63;
    float m = part[0][j][k2] + part[1][j][k2] + part[2][j][k2] +
              part[3][j][k2] + part[4][j][k2];
    int ed = eids[j];
    int b = ed >> 7, e = ed & (E_ - 1);
    int h = heads[(b * L_ + l) * E_ + e];
    size_t row = (size_t)b * S_ + h;
    atomicAdd(&accum[row * DEP_ + k2], m);
    if (k2 == 0) atomicAdd(&cntbuf[row], 1.0f);
  }
}

// ---------------------------------------------------------------------------
// K_A: assignment (avg) for touched heads + fused clear of the other-parity
// accum/cnt rows for layer l+1 (race-free: double-buffered).
// ---------------------------------------------------------------------------
__global__ void k_avg(const int* __restrict__ heads, int l,
                      const float* __restrict__ accumP, const float* __restrict__ cntP,
                      float* __restrict__ child,
                      float* __restrict__ accumQ, float* __restrict__ cntQ,
                      int do_clear_next) {
  int gid = blockIdx.x * blockDim.x + threadIdx.x;
  int ed = gid >> 6, k = gid & 63;
  int b = ed >> 7, e = ed & (E_ - 1);
  int h = heads[(b * L_ + l) * E_ + e];
  size_t row = (size_t)b * S_ + h;
  float c = cntP[row];
  child[row * DEP_ + k] = accumP[row * DEP_ + k] / fmaxf(c, 1.0f);
  if (do_clear_next) {
    int h2 = heads[(b * L_ + (l + 1)) * E_ + e];
    size_t row2 = (size_t)b * S_ + h2;
    accumQ[row2 * DEP_ + k] = 0.0f;
    if (k == 0) cntQ[row2] = 0.0f;
  }
}

// ---------------------------------------------------------------------------
// K_O: out = concat(context, child), float4 flat copy
// ---------------------------------------------------------------------------
__global__ void k_out(const float4* __restrict__ ctx4,
                      const float4* __restrict__ chd4,
                      float4* __restrict__ out4) {
  int i = blockIdx.x * blockDim.x + threadIdx.x;
  constexpr int TOT4 = B_ * S_ * (FEAT_ / 4);   // 2,621,440
  if (i >= TOT4) return;
  int row = i / 80;
  int c4 = i - row * 80;
  out4[i] = (c4 < 64) ? ctx4[(size_t)row * 64 + c4]
                      : chd4[(size_t)row * 16 + (c4 - 64)];
}

extern "C" void kernel_launch(void* const* d_in, const int* in_sizes, int n_in,
                              void* d_out, int out_size, void* d_ws, size_t ws_size,
                              hipStream_t stream) {
  const float* context = (const float*)d_in[0];
  const float* dep_W   = (const float*)d_in[1];
  const int*   heads   = (const int*)d_in[2];
  const int*   tails   = (const int*)d_in[3];
  const int*   rels    = (const int*)d_in[4];
  float* out = (float*)d_out;

  float* ws = (float*)d_ws;
  float* child  = ws + OFF_CHILD;
  float* accum0 = ws + OFF_ACC0;
  float* cnt0   = ws + OFF_CNT0;
  float* accum1 = ws + OFF_ACC1;
  float* cnt1   = ws + OFF_CNT1;
  float* WT2    = ws + OFF_WT;
  int*   sorted = (int*)(ws + OFF_SORT);
  int4*  chunks = (int4*)(ws + OFF_CHUNK);

  // Prepasses (independent of child): W re-layout, per-layer binning, zeroing.
  {
    int totW = R_ * FEAT_ * DEP_;
    k_transpose<<<(totW + 255) / 256, 256, 0, stream>>>(dep_W, WT2);
    k_bin<<<L_, 256, 0, stream>>>(rels, sorted, chunks);
    int n = (int)(N_CHILD + N_ACC + N_CNT);   // child + accum0 + cnt0
    k_zero<<<(n + 255) / 256, 256, 0, stream>>>(child, n);
  }

  int blocks_edge = NEDGE_ * 64 / 256;   // 1024
  for (int l = 0; l < L_; ++l) {
    float* accP = (l & 1) ? accum1 : accum0;
    float* cntP = (l & 1) ? cnt1 : cnt0;
    float* accQ = (l & 1) ? accum0 : accum1;
    float* cntQ = (l & 1) ? cnt0 : cnt1;
    k_msg<<<NCH_, 320, 0, stream>>>(context, WT2, heads, tails, child,
                                    sorted, chunks, l, accP, cntP);
    int do_clear = (l + 1 < L_) ? 1 : 0;
    k_avg<<<blocks_edge, 256, 0, stream>>>(heads, l, accP, cntP, child,
                                           accQ, cntQ, do_clear);
  }

  constexpr int TOT4 = B_ * S_ * (FEAT_ / 4);
  k_out<<<(TOT4 + 255) / 256, 256, 0, stream>>>(
      (const float4*)context, (const float4*)child, (float4*)out);
}